// Round 11
// baseline (72.005 us; speedup 1.0000x reference)
//
#include <hip/hip_runtime.h>
#include <math.h>

// GAT aggregator: out = relu( deg>0 ? segment_softmax(leaky(s_src[src]+s_dst[dst])) @ Wh[dst] : Wh )
// N=100000, E=1600000, D=64. edge_src is SORTED.
// wh: bf16 MFMA (16x16x32). agg: 8-lane group per node, 2-stage pipelined gather,
// nontemporal out stores (via clang ext_vector f32x4 — HIP float4 is rejected).

#define DD 64

typedef __attribute__((ext_vector_type(8))) short bf16x8;
typedef __attribute__((ext_vector_type(4))) float f32x4;

static __device__ __forceinline__ unsigned short f2bf(float x) {
    unsigned int u = __float_as_uint(x);
    u += 0x7fffu + ((u >> 16) & 1u);          // RNE
    return (unsigned short)(u >> 16);
}

static __device__ __forceinline__ bf16x8 cvt8(float4 x0, float4 x1) {
    bf16x8 f;
    f[0] = (short)f2bf(x0.x); f[1] = (short)f2bf(x0.y);
    f[2] = (short)f2bf(x0.z); f[3] = (short)f2bf(x0.w);
    f[4] = (short)f2bf(x1.x); f[5] = (short)f2bf(x1.y);
    f[6] = (short)f2bf(x1.z); f[7] = (short)f2bf(x1.w);
    return f;
}

static __device__ __forceinline__ void fma8(float p, uint4 q, float* acc) {
    acc[0] = fmaf(p, __uint_as_float(q.x << 16),          acc[0]);
    acc[1] = fmaf(p, __uint_as_float(q.x & 0xffff0000u),  acc[1]);
    acc[2] = fmaf(p, __uint_as_float(q.y << 16),          acc[2]);
    acc[3] = fmaf(p, __uint_as_float(q.y & 0xffff0000u),  acc[3]);
    acc[4] = fmaf(p, __uint_as_float(q.z << 16),          acc[4]);
    acc[5] = fmaf(p, __uint_as_float(q.z & 0xffff0000u),  acc[5]);
    acc[6] = fmaf(p, __uint_as_float(q.w << 16),          acc[6]);
    acc[7] = fmaf(p, __uint_as_float(q.w & 0xffff0000u),  acc[7]);
}

// ---------------- Kernel 1: Whb = bf16(h @ W^T) via MFMA; s_src/s_dst from D-frags --
__global__ __launch_bounds__(256) void wh_kernel(
    const float* __restrict__ h, const float* __restrict__ W,
    const float* __restrict__ a, unsigned short* __restrict__ Whb,
    float* __restrict__ s_src, float* __restrict__ s_dst, int N)
{
    __shared__ unsigned short pack[4][16][72];   // per-wave repack buffer

    int w    = threadIdx.x >> 6;
    int lane = threadIdx.x & 63;
    int lr   = lane & 15;                        // row-in-tile (A) / col-in-tile (B,D)
    int lk   = lane >> 4;                        // k-group (A,B) / row-group (D)
    int m0   = blockIdx.x * 64 + w * 16;
    if (m0 >= N) return;                         // wave-uniform exit; no barriers used

    // B-frags: whole W (64x64) as 8 frags (t = col tile, q = k half)
    bf16x8 bfr[4][2];
    #pragma unroll
    for (int t = 0; t < 4; ++t) {
        const float* wrow = W + (size_t)(t * 16 + lr) * DD;
        #pragma unroll
        for (int q = 0; q < 2; ++q) {
            float4 x0 = *(const float4*)(wrow + q * 32 + lk * 8);
            float4 x1 = *(const float4*)(wrow + q * 32 + lk * 8 + 4);
            bfr[t][q] = cvt8(x0, x1);
        }
    }

    // A-frags: this wave's 16 h rows
    int arow = m0 + lr; if (arow >= N) arow = N - 1;
    const float* hrow = h + (size_t)arow * DD;
    bf16x8 afr[2];
    #pragma unroll
    for (int q = 0; q < 2; ++q) {
        float4 x0 = *(const float4*)(hrow + q * 32 + lk * 8);
        float4 x1 = *(const float4*)(hrow + q * 32 + lk * 8 + 4);
        afr[q] = cvt8(x0, x1);
    }

    // 8 MFMA: 4 col-tiles x K=64
    f32x4 acc[4];
    #pragma unroll
    for (int t = 0; t < 4; ++t) {
        f32x4 z = {0.f, 0.f, 0.f, 0.f};
        z = __builtin_amdgcn_mfma_f32_16x16x32_bf16(afr[0], bfr[t][0], z, 0, 0, 0);
        acc[t] = __builtin_amdgcn_mfma_f32_16x16x32_bf16(afr[1], bfr[t][1], z, 0, 0, 0);
    }

    // scores: lane has col = t*16+lr, rows lk*4+r
    float av0[4], av1[4];
    #pragma unroll
    for (int t = 0; t < 4; ++t) {
        av0[t] = a[t * 16 + lr];
        av1[t] = a[DD + t * 16 + lr];
    }
    #pragma unroll
    for (int r = 0; r < 4; ++r) {
        float ssrc = 0.f, sdst = 0.f;
        #pragma unroll
        for (int t = 0; t < 4; ++t) {
            ssrc = fmaf(acc[t][r], av0[t], ssrc);
            sdst = fmaf(acc[t][r], av1[t], sdst);
        }
        #pragma unroll
        for (int off = 1; off < 16; off <<= 1) {
            ssrc += __shfl_xor(ssrc, off);
            sdst += __shfl_xor(sdst, off);
        }
        if (lr == 0) {
            int row = m0 + lk * 4 + r;
            if (row < N) { s_src[row] = ssrc; s_dst[row] = sdst; }
        }
    }

    // repack D-frags -> bf16 rows (same-wave LDS, no barrier)
    #pragma unroll
    for (int t = 0; t < 4; ++t)
        #pragma unroll
        for (int r = 0; r < 4; ++r)
            pack[w][lk * 4 + r][t * 16 + lr] = f2bf(acc[t][r]);

    int prow = lane >> 2;                        // 0..15
    int pcol = (lane & 3) * 16;                  // 0,16,32,48
    int grow = m0 + prow;
    if (grow < N) {
        uint4 v0 = *(const uint4*)&pack[w][prow][pcol];
        uint4 v1 = *(const uint4*)&pack[w][prow][pcol + 8];
        *(uint4*)(Whb + (size_t)grow * DD + pcol)     = v0;
        *(uint4*)(Whb + (size_t)grow * DD + pcol + 8) = v1;
    }
}

// ---------------- Kernel 2: edge-parallel row_ptr boundary scatter -----------------
__global__ __launch_bounds__(256) void rowptr_kernel(
    const int* __restrict__ src, int* __restrict__ row_ptr, int E, int N)
{
    int i = blockIdx.x * 256 + threadIdx.x;
    if (i >= E) return;
    int s   = src[i];
    int nxt = (i + 1 < E) ? src[i + 1] : N;
    if (i == 0)
        for (int n = 0; n <= s; ++n) row_ptr[n] = 0;
    for (int n = s + 1; n <= nxt; ++n) row_ptr[n] = i + 1;
}

// ---------------- Kernel 3: 8-lane group per node; 2-stage pipelined gather --------
__global__ __launch_bounds__(256) void agg_kernel(
    const unsigned short* __restrict__ Whb, const float* __restrict__ s_src,
    const float* __restrict__ s_dst, const int* __restrict__ edge_dst,
    const int* __restrict__ row_ptr, float* __restrict__ out, int N)
{
    int tid  = blockIdx.x * 256 + threadIdx.x;
    int node = tid >> 3;                         // 8 lanes per node
    int c8   = threadIdx.x & 7;                  // this lane owns feats c8*8..c8*8+7
    if (node >= N) return;

    int lo = row_ptr[node], hi = row_ptr[node + 1];
    size_t obase = (size_t)node * DD;
    f32x4* outv = (f32x4*)(out + obase);         // clang vector type: nt-store OK

    if (lo == hi) {                              // no outgoing edges: relu(Wh row)
        uint4 q = *(const uint4*)(Whb + obase + c8 * 8);
        float v[8] = {};
        fma8(1.f, q, v);
        f32x4 o0 = {fmaxf(v[0], 0.f), fmaxf(v[1], 0.f), fmaxf(v[2], 0.f), fmaxf(v[3], 0.f)};
        f32x4 o1 = {fmaxf(v[4], 0.f), fmaxf(v[5], 0.f), fmaxf(v[6], 0.f), fmaxf(v[7], 0.f)};
        __builtin_nontemporal_store(o0, outv + c8 * 2);
        __builtin_nontemporal_store(o1, outv + c8 * 2 + 1);
        return;
    }

    float ss    = s_src[node];
    float denom = 0.f;                           // identical in all 8 lanes
    float acc[8] = {};

    uint4 qA[4], qB[4];
    float pA[4], pB[4];

    auto LOADX = [&](uint4* q, float* p, int base) {
        #pragma unroll
        for (int k = 0; k < 4; ++k) {
            int ii = (base + k < hi) ? base + k : hi - 1;   // clamp: dup loads, p=0
            int d  = __builtin_nontemporal_load(&edge_dst[ii]);
            float sd = s_dst[d];
            q[k] = *(const uint4*)(Whb + (size_t)d * DD + c8 * 8);
            float x = ss + sd;
            x = x > 0.f ? x : 0.2f * x;          // leaky_relu(0.2)
            p[k] = (base + k < hi) ? __expf(x) : 0.f;
        }
    };
    auto CONS = [&](uint4* q, float* p) {
        denom += (p[0] + p[1]) + (p[2] + p[3]);
        fma8(p[0], q[0], acc);
        fma8(p[1], q[1], acc);
        fma8(p[2], q[2], acc);
        fma8(p[3], q[3], acc);
    };

    int nb = (hi - lo + 3) >> 2;                 // 4-edge blocks
    LOADX(qA, pA, lo);
    int bi = 1;
    for (; bi + 1 < nb; bi += 2) {               // load B while consuming A, and vice versa
        LOADX(qB, pB, lo + bi * 4);
        CONS(qA, pA);
        LOADX(qA, pA, lo + (bi + 1) * 4);
        CONS(qB, pB);
    }
    if (bi < nb) {
        LOADX(qB, pB, lo + bi * 4);
        CONS(qA, pA);
        CONS(qB, pB);
    } else {
        CONS(qA, pA);
    }

    float inv = 1.f / denom;
    f32x4 o0 = {fmaxf(acc[0] * inv, 0.f), fmaxf(acc[1] * inv, 0.f),
                fmaxf(acc[2] * inv, 0.f), fmaxf(acc[3] * inv, 0.f)};
    f32x4 o1 = {fmaxf(acc[4] * inv, 0.f), fmaxf(acc[5] * inv, 0.f),
                fmaxf(acc[6] * inv, 0.f), fmaxf(acc[7] * inv, 0.f)};
    __builtin_nontemporal_store(o0, outv + c8 * 2);
    __builtin_nontemporal_store(o1, outv + c8 * 2 + 1);
}

// ---------------- launch ----------------
extern "C" void kernel_launch(void* const* d_in, const int* in_sizes, int n_in,
                              void* d_out, int out_size, void* d_ws, size_t ws_size,
                              hipStream_t stream)
{
    const float* h    = (const float*)d_in[0];
    const float* W    = (const float*)d_in[1];
    const float* a    = (const float*)d_in[2];
    const int*   esrc = (const int*)d_in[3];
    const int*   edst = (const int*)d_in[4];

    int N = in_sizes[0] / DD;
    int E = in_sizes[3];
    float* out = (float*)d_out;

    // ws layout: Whb (N*64 bf16) | s_src (N f32) | s_dst (N f32) | row_ptr (N+1)
    unsigned short* Whb = (unsigned short*)d_ws;          // 12.8 MB
    float* s_src   = (float*)(Whb + (size_t)N * DD);      // 0.4 MB
    float* s_dst   = s_src + N;                           // 0.4 MB
    int*   row_ptr = (int*)(s_dst + N);                   // 0.4 MB

    wh_kernel<<<(N + 63) / 64, 256, 0, stream>>>(h, W, a, Whb, s_src, s_dst, N);
    rowptr_kernel<<<(E + 255) / 256, 256, 0, stream>>>(esrc, row_ptr, E, N);
    int aggThreads = N * 8;
    agg_kernel<<<(aggThreads + 255) / 256, 256, 0, stream>>>(Whb, s_src, s_dst, edst, row_ptr, out, N);
}

// Round 12
// 62.288 us; speedup vs baseline: 1.1560x; 1.1560x over previous
//
#include <hip/hip_runtime.h>
#include <math.h>

// GAT aggregator: out = relu( deg>0 ? segment_softmax(leaky(s_src[src]+s_dst[dst])) @ Wh[dst] : Wh )
// N=100000, E=1600000, D=64. edge_src is SORTED.
// wh: bf16 MFMA (16x16x32), output table quantized to int8 + per-row scale (64B rows).
// agg: R9 structure — one 8-lane group per node, 4-wide ILP, int8 rows.

#define DD 64

typedef __attribute__((ext_vector_type(8))) short bf16x8;
typedef __attribute__((ext_vector_type(4))) float f32x4;

static __device__ __forceinline__ unsigned short f2bf(float x) {
    unsigned int u = __float_as_uint(x);
    u += 0x7fffu + ((u >> 16) & 1u);          // RNE
    return (unsigned short)(u >> 16);
}

static __device__ __forceinline__ bf16x8 cvt8(float4 x0, float4 x1) {
    bf16x8 f;
    f[0] = (short)f2bf(x0.x); f[1] = (short)f2bf(x0.y);
    f[2] = (short)f2bf(x0.z); f[3] = (short)f2bf(x0.w);
    f[4] = (short)f2bf(x1.x); f[5] = (short)f2bf(x1.y);
    f[6] = (short)f2bf(x1.z); f[7] = (short)f2bf(x1.w);
    return f;
}

// ps = p * row_scale; q = 8 int8 features (uint2)
static __device__ __forceinline__ void fma8_i8(float ps, uint2 q, float* acc) {
    #pragma unroll
    for (int j = 0; j < 4; ++j) {
        int v0 = (int)((q.x << (24 - 8 * j)) ) >> 24;   // sign-extended byte j
        int v1 = (int)((q.y << (24 - 8 * j)) ) >> 24;
        acc[j]     = fmaf(ps, (float)v0, acc[j]);
        acc[4 + j] = fmaf(ps, (float)v1, acc[4 + j]);
    }
}

// ---------------- Kernel 1: Whq = int8(h @ W^T) + per-row scale; scores ------------
__global__ __launch_bounds__(256) void wh_kernel(
    const float* __restrict__ h, const float* __restrict__ W,
    const float* __restrict__ a, signed char* __restrict__ Whq,
    float* __restrict__ s_src, float2* __restrict__ sdsc, int N)
{
    __shared__ signed char pack8[4][16][80];     // per-wave repack (rows 16B-aligned)

    int w    = threadIdx.x >> 6;
    int lane = threadIdx.x & 63;
    int lr   = lane & 15;                        // row-in-tile (A) / col-in-tile (B,D)
    int lk   = lane >> 4;                        // k-group (A,B) / row-group (D)
    int m0   = blockIdx.x * 64 + w * 16;
    if (m0 >= N) return;                         // wave-uniform exit; no barriers used

    // B-frags: whole W (64x64) as 8 frags (t = col tile, q = k half)
    bf16x8 bfr[4][2];
    #pragma unroll
    for (int t = 0; t < 4; ++t) {
        const float* wrow = W + (size_t)(t * 16 + lr) * DD;
        #pragma unroll
        for (int q = 0; q < 2; ++q) {
            float4 x0 = *(const float4*)(wrow + q * 32 + lk * 8);
            float4 x1 = *(const float4*)(wrow + q * 32 + lk * 8 + 4);
            bfr[t][q] = cvt8(x0, x1);
        }
    }

    // A-frags: this wave's 16 h rows
    int arow = m0 + lr; if (arow >= N) arow = N - 1;
    const float* hrow = h + (size_t)arow * DD;
    bf16x8 afr[2];
    #pragma unroll
    for (int q = 0; q < 2; ++q) {
        float4 x0 = *(const float4*)(hrow + q * 32 + lk * 8);
        float4 x1 = *(const float4*)(hrow + q * 32 + lk * 8 + 4);
        afr[q] = cvt8(x0, x1);
    }

    // 8 MFMA: 4 col-tiles x K=64
    f32x4 acc[4];
    #pragma unroll
    for (int t = 0; t < 4; ++t) {
        f32x4 z = {0.f, 0.f, 0.f, 0.f};
        z = __builtin_amdgcn_mfma_f32_16x16x32_bf16(afr[0], bfr[t][0], z, 0, 0, 0);
        acc[t] = __builtin_amdgcn_mfma_f32_16x16x32_bf16(afr[1], bfr[t][1], z, 0, 0, 0);
    }

    // per-row: scores + rowmax + int8 quant.  lane has col = t*16+lr, rows lk*4+r
    float av0[4], av1[4];
    #pragma unroll
    for (int t = 0; t < 4; ++t) {
        av0[t] = a[t * 16 + lr];
        av1[t] = a[DD + t * 16 + lr];
    }
    #pragma unroll
    for (int r = 0; r < 4; ++r) {
        float ssrc = 0.f, sdst = 0.f, am = 0.f;
        #pragma unroll
        for (int t = 0; t < 4; ++t) {
            ssrc = fmaf(acc[t][r], av0[t], ssrc);
            sdst = fmaf(acc[t][r], av1[t], sdst);
            am   = fmaxf(am, fabsf(acc[t][r]));
        }
        #pragma unroll
        for (int off = 1; off < 16; off <<= 1) { // reduce over the 16 col-lanes
            ssrc += __shfl_xor(ssrc, off);
            sdst += __shfl_xor(sdst, off);
            am    = fmaxf(am, __shfl_xor(am, off));
        }
        float qinv = am > 0.f ? 127.f / am : 0.f;
        float sc   = am > 0.f ? am / 127.f : 0.f;
        #pragma unroll
        for (int t = 0; t < 4; ++t)
            pack8[w][lk * 4 + r][t * 16 + lr] =
                (signed char)__float2int_rn(acc[t][r] * qinv);
        if (lr == 0) {
            int row = m0 + lk * 4 + r;
            if (row < N) {
                s_src[row] = ssrc;
                sdsc[row]  = make_float2(sdst, sc);
            }
        }
    }

    // store int8 rows: 64B/row, 4 lanes x 16B per row (same-wave LDS, no barrier)
    int prow = lane >> 2;                        // 0..15
    int pseg = lane & 3;                         // 16B segment
    int grow = m0 + prow;
    if (grow < N) {
        uint4 v = *(const uint4*)&pack8[w][prow][pseg * 16];
        *(uint4*)(Whq + (size_t)grow * DD + pseg * 16) = v;
    }
}

// ---------------- Kernel 2: edge-parallel row_ptr boundary scatter -----------------
__global__ __launch_bounds__(256) void rowptr_kernel(
    const int* __restrict__ src, int* __restrict__ row_ptr, int E, int N)
{
    int i = blockIdx.x * 256 + threadIdx.x;
    if (i >= E) return;
    int s   = src[i];
    int nxt = (i + 1 < E) ? src[i + 1] : N;
    if (i == 0)
        for (int n = 0; n <= s; ++n) row_ptr[n] = 0;
    for (int n = s + 1; n <= nxt; ++n) row_ptr[n] = i + 1;
}

// ---------------- Kernel 3: one 8-lane group per node; int8 rows, 4-wide ILP -------
__global__ __launch_bounds__(256) void agg_kernel(
    const signed char* __restrict__ Whq, const float* __restrict__ s_src,
    const float2* __restrict__ sdsc, const int* __restrict__ edge_dst,
    const int* __restrict__ row_ptr, float* __restrict__ out, int N)
{
    int tid  = blockIdx.x * 256 + threadIdx.x;
    int node = tid >> 3;                         // 8 lanes per node
    int c8   = threadIdx.x & 7;                  // this lane owns feats c8*8..c8*8+7
    if (node >= N) return;

    int lo = row_ptr[node], hi = row_ptr[node + 1];
    size_t obase = (size_t)node * DD;

    if (lo == hi) {                              // no outgoing edges: relu(Wh row)
        uint2 q = *(const uint2*)(Whq + obase + c8 * 8);
        float sc = sdsc[node].y;
        float v[8] = {};
        fma8_i8(sc, q, v);
        float4 o0 = make_float4(fmaxf(v[0], 0.f), fmaxf(v[1], 0.f),
                                fmaxf(v[2], 0.f), fmaxf(v[3], 0.f));
        float4 o1 = make_float4(fmaxf(v[4], 0.f), fmaxf(v[5], 0.f),
                                fmaxf(v[6], 0.f), fmaxf(v[7], 0.f));
        ((float4*)(out + obase))[c8 * 2]     = o0;
        ((float4*)(out + obase))[c8 * 2 + 1] = o1;
        return;
    }

    float ss    = s_src[node];
    float denom = 0.f;                           // identical in all 8 lanes
    float acc[8] = {};

    for (int e = lo; e < hi; e += 4) {           // 4 independent row-gathers in flight
        int i1 = (e + 1 < hi) ? e + 1 : hi - 1;  // clamp: dup loads, p forced 0
        int i2 = (e + 2 < hi) ? e + 2 : hi - 1;
        int i3 = (e + 3 < hi) ? e + 3 : hi - 1;
        int d0 = edge_dst[e],  d1 = edge_dst[i1];
        int d2 = edge_dst[i2], d3 = edge_dst[i3];
        float2 v0 = sdsc[d0], v1 = sdsc[d1], v2 = sdsc[d2], v3 = sdsc[d3];
        uint2 q0 = *(const uint2*)(Whq + (size_t)d0 * DD + c8 * 8);
        uint2 q1 = *(const uint2*)(Whq + (size_t)d1 * DD + c8 * 8);
        uint2 q2 = *(const uint2*)(Whq + (size_t)d2 * DD + c8 * 8);
        uint2 q3 = *(const uint2*)(Whq + (size_t)d3 * DD + c8 * 8);
        float x0 = ss + v0.x, x1 = ss + v1.x, x2 = ss + v2.x, x3 = ss + v3.x;
        x0 = x0 > 0.f ? x0 : 0.2f * x0;          // leaky_relu(0.2)
        x1 = x1 > 0.f ? x1 : 0.2f * x1;
        x2 = x2 > 0.f ? x2 : 0.2f * x2;
        x3 = x3 > 0.f ? x3 : 0.2f * x3;
        float p0 = __expf(x0);                   // |e| small -> skip max-shift
        float p1 = (e + 1 < hi) ? __expf(x1) : 0.f;
        float p2 = (e + 2 < hi) ? __expf(x2) : 0.f;
        float p3 = (e + 3 < hi) ? __expf(x3) : 0.f;
        denom += (p0 + p1) + (p2 + p3);
        fma8_i8(p0 * v0.y, q0, acc);
        fma8_i8(p1 * v1.y, q1, acc);
        fma8_i8(p2 * v2.y, q2, acc);
        fma8_i8(p3 * v3.y, q3, acc);
    }

    float inv = 1.f / denom;
    float4 o0 = make_float4(fmaxf(acc[0] * inv, 0.f), fmaxf(acc[1] * inv, 0.f),
                            fmaxf(acc[2] * inv, 0.f), fmaxf(acc[3] * inv, 0.f));
    float4 o1 = make_float4(fmaxf(acc[4] * inv, 0.f), fmaxf(acc[5] * inv, 0.f),
                            fmaxf(acc[6] * inv, 0.f), fmaxf(acc[7] * inv, 0.f));
    ((float4*)(out + obase))[c8 * 2]     = o0;
    ((float4*)(out + obase))[c8 * 2 + 1] = o1;
}

// ---------------- launch ----------------
extern "C" void kernel_launch(void* const* d_in, const int* in_sizes, int n_in,
                              void* d_out, int out_size, void* d_ws, size_t ws_size,
                              hipStream_t stream)
{
    const float* h    = (const float*)d_in[0];
    const float* W    = (const float*)d_in[1];
    const float* a    = (const float*)d_in[2];
    const int*   esrc = (const int*)d_in[3];
    const int*   edst = (const int*)d_in[4];

    int N = in_sizes[0] / DD;
    int E = in_sizes[3];
    float* out = (float*)d_out;

    // ws layout: Whq (N*64 i8) | s_src (N f32) | sdsc (N float2) | row_ptr (N+1)
    signed char* Whq = (signed char*)d_ws;                // 6.4 MB
    float*  s_src    = (float*)(Whq + (size_t)N * DD);    // 0.4 MB
    float2* sdsc     = (float2*)(s_src + N);              // 0.8 MB (8B-aligned: N*64+4N div 8)
    int*    row_ptr  = (int*)(sdsc + N);                  // 0.4 MB

    wh_kernel<<<(N + 63) / 64, 256, 0, stream>>>(h, W, a, Whq, s_src, sdsc, N);
    rowptr_kernel<<<(E + 255) / 256, 256, 0, stream>>>(esrc, row_ptr, E, N);
    int aggThreads = N * 8;
    agg_kernel<<<(aggThreads + 255) / 256, 256, 0, stream>>>(Whq, s_src, sdsc, edst, row_ptr, out, N);
}